// Round 1
// baseline (606.781 us; speedup 1.0000x reference)
//
#include <hip/hip_runtime.h>
#include <math.h>

#define H_ 128
#define W_ 128
#define C_ 64
#define O_ 64
#define B_ 8
#define K2_ 9
#define HWSZ (H_*W_)

// ---------------------------------------------------------------------------
// Kernel P: weight prep.
//  wt  (K2, C, O)  : sample-GEMM weights, contiguous in o -> clean s_load.
//  wom (C, 27, 9)  : offset(18)+mask(9) conv weights contiguous per channel
//                    (old layout had stride-2304B s_loads -> scalar-cache shred).
// ---------------------------------------------------------------------------
__global__ __launch_bounds__(256) void prep_weights_k(
    const float* __restrict__ w, const float* __restrict__ w_off,
    const float* __restrict__ w_mod, float* __restrict__ wt,
    float* __restrict__ wom) {
    int id = blockIdx.x * 256 + threadIdx.x;
    if (id < K2_ * C_ * O_) {              // id = k*C*O + c*O + o
        int o = id & (O_ - 1);
        int c = (id >> 6) & (C_ - 1);
        int k = id / (C_ * O_);
        wt[id] = w[(o * C_ + c) * K2_ + k];
    }
    int id2 = id - K2_ * C_ * O_;
    if (id2 >= 0 && id2 < C_ * 243) {      // id2 = c*243 + t*9 + k
        int k = id2 % 9;
        int tt = (id2 / 9) % 27;
        int c = id2 / 243;
        float v = (tt < 18) ? w_off[(tt * C_ + c) * K2_ + k]
                            : w_mod[((tt - 18) * C_ + c) * K2_ + k];
        wom[id2] = v;
    }
}

// ---------------------------------------------------------------------------
// Kernel A: 3x3 conv -> 18 offset + 9 mask channels, fused coord calc.
// v2: 4-way channel split (c-split duplicates nothing), 128-pixel strips,
// grid 1024 blocks -> 32 waves/CU target (was grid-capped at 16).
// Sequential-add LDS reduce keeps LDS at 13.8 KB.
// Explicit v-prefetch hides the 9 gather loads under the 243-FMA block.
// Weights from wom: 243 contiguous floats per channel -> dwordx16 stream.
// ---------------------------------------------------------------------------
__global__ __launch_bounds__(512) void conv_offmask_k(
    const float* __restrict__ x,
    const float* __restrict__ wom, const float* __restrict__ b_off,
    const float* __restrict__ b_mod,
    float* __restrict__ pyA, float* __restrict__ pxA, float* __restrict__ mA) {
    __shared__ float red[27 * 128];        // 13.8 KB

    int b     = blockIdx.x & 7;            // batch -> XCD (L2 locality)
    int strip = blockIdx.x >> 3;           // 0..127 : 1-row strip
    int tid   = threadIdx.x;
    int t     = tid & 127;                 // pixel within strip
    int q     = tid >> 7;                  // 0..3 -> channel quarter
    int c0    = __builtin_amdgcn_readfirstlane(q << 4);  // wave-uniform SGPR
    int p     = strip * 128 + t;
    int w     = p & (W_ - 1);
    int h     = p >> 7;

    int offs[9];
    float valid[9];
#pragma unroll
    for (int i = 0; i < 9; i++) {
        int dy = i / 3 - 1, dx = i % 3 - 1;
        int yy = h + dy, xx = w + dx;
        bool v = (yy >= 0 && yy < H_ && xx >= 0 && xx < W_);
        int yc = min(max(yy, 0), H_ - 1);
        int xc = min(max(xx, 0), W_ - 1);
        offs[i] = yc * W_ + xc;
        valid[i] = v ? 1.0f : 0.0f;
    }

    float acc[27];
#pragma unroll
    for (int o = 0; o < 27; o++) acc[o] = 0.0f;

    const float* xb = x + (b * C_ + c0) * HWSZ;

    // prefetch gathers for c=0
    float v[9];
#pragma unroll
    for (int i = 0; i < 9; i++) v[i] = xb[offs[i]] * valid[i];

    for (int c = 0; c < 16; c++) {
        // issue next channel's gathers; they complete under the FMA block
        const float* xn = xb + min(c + 1, 15) * HWSZ;
        float vn[9];
#pragma unroll
        for (int i = 0; i < 9; i++) vn[i] = xn[offs[i]] * valid[i];

        const float* wc = wom + (c0 + c) * 243;   // uniform -> s_load stream
#pragma unroll
        for (int o = 0; o < 27; o++) {
#pragma unroll
            for (int kk = 0; kk < 9; kk++) acc[o] += v[kk] * wc[o * 9 + kk];
        }
#pragma unroll
        for (int i = 0; i < 9; i++) v[i] = vn[i];
    }

    // sequential-add reduce: q3 writes, q2 adds, q1 adds, q0 finishes
    if (q == 3) {
#pragma unroll
        for (int o = 0; o < 27; o++) red[o * 128 + t] = acc[o];
    }
    __syncthreads();
    if (q == 2) {
#pragma unroll
        for (int o = 0; o < 27; o++) red[o * 128 + t] += acc[o];
    }
    __syncthreads();
    if (q == 1) {
#pragma unroll
        for (int o = 0; o < 27; o++) red[o * 128 + t] += acc[o];
    }
    __syncthreads();
    if (q == 0) {
#pragma unroll
        for (int k = 0; k < 9; k++) {
            float dy = acc[2 * k]     + red[(2 * k)     * 128 + t] + b_off[2 * k];
            float dx = acc[2 * k + 1] + red[(2 * k + 1) * 128 + t] + b_off[2 * k + 1];
            float mm = acc[18 + k]    + red[(18 + k)    * 128 + t] + b_mod[k];
            float mask = 2.0f / (1.0f + __expf(-mm));
            float py = dy + (float)h - 1.0f + (float)(k / 3);
            float px = dx + (float)w - 1.0f + (float)(k % 3);
            int idx = (b * 9 + k) * HWSZ + p;
            pyA[idx] = py;
            pxA[idx] = px;
            mA[idx] = mask;
        }
    }
}

// ---------------------------------------------------------------------------
// Kernel B: bilinear sample + masked reduction GEMM.
// v2: split OUTPUTS (o) across the two halves instead of channels:
//  - acc[32]/thread (was 64) -> lower VGPR, weight chunk 32 floats ->
//    fits double-buffered in the SGPR budget (was 64, single-buffered stall).
//  - no 64 KB LDS reduce, no barrier.
//  - gathers batched 4 channels deep (16 loads in flight) with an explicit
//    cross-iteration double-buffer: next group's loads issue before this
//    group's FMAs, hiding ~400cy L2 latency under 128 FMAs.
//  - next-k coords prefetched at top of the c-loop.
// Cost: gathers duplicated 2x across o-halves (L1/L2 traffic, HBM is 5% busy).
// ---------------------------------------------------------------------------
__global__ __launch_bounds__(512) void sample_gemm_k(
    const float* __restrict__ x,
    const float* __restrict__ pyA, const float* __restrict__ pxA,
    const float* __restrict__ mA, const float* __restrict__ wt,
    const float* __restrict__ bias, float* __restrict__ out) {

    int b     = blockIdx.x & 7;
    int strip = blockIdx.x >> 3;           // 0..63 : 2-row strip
    int tid   = threadIdx.x;
    int t     = tid & 255;
    int half  = tid >> 8;
    int o0    = __builtin_amdgcn_readfirstlane(half << 5);  // output half
    int p     = strip * 256 + t;

    float acc[32];
#pragma unroll
    for (int o = 0; o < 32; o++) acc[o] = 0.0f;

    const float* xb = x + b * C_ * HWSZ;

    int idx0 = b * 9 * HWSZ + p;
    float py = pyA[idx0], px = pxA[idx0], m = mA[idx0];

    for (int k = 0; k < 9; k++) {
        // prefetch next k's coords (in flight across the whole c-loop)
        int idxn = (b * 9 + min(k + 1, 8)) * HWSZ + p;
        float pyn = pyA[idxn], pxn = pxA[idxn], mn = mA[idxn];

        float y0f = floorf(py), x0f = floorf(px);
        float wy = py - y0f, wx = px - x0f;
        int y0 = (int)y0f, x0 = (int)x0f;
        int y1 = y0 + 1, x1 = x0 + 1;
        float vy0 = (y0 >= 0 && y0 < H_) ? 1.0f : 0.0f;
        float vy1 = (y1 >= 0 && y1 < H_) ? 1.0f : 0.0f;
        float vx0 = (x0 >= 0 && x0 < W_) ? 1.0f : 0.0f;
        float vx1 = (x1 >= 0 && x1 < W_) ? 1.0f : 0.0f;
        int y0c = min(max(y0, 0), H_ - 1), y1c = min(max(y1, 0), H_ - 1);
        int x0c = min(max(x0, 0), W_ - 1), x1c = min(max(x1, 0), W_ - 1);

        float w00 = (1.0f - wy) * (1.0f - wx) * vy0 * vx0 * m;
        float w01 = (1.0f - wy) * wx * vy0 * vx1 * m;
        float w10 = wy * (1.0f - wx) * vy1 * vx0 * m;
        float w11 = wy * wx * vy1 * vx1 * m;

        int o00 = y0c * W_ + x0c, o01 = y0c * W_ + x1c;
        int o10 = y1c * W_ + x0c, o11 = y1c * W_ + x1c;

        const float* wp = wt + k * (C_ * O_) + o0;    // uniform -> s_load

        // prime the gather double-buffer with channels 0..3
        float a[16];
#pragma unroll
        for (int u = 0; u < 4; u++) {
            const float* xc = xb + u * HWSZ;
            a[u * 4 + 0] = xc[o00]; a[u * 4 + 1] = xc[o01];
            a[u * 4 + 2] = xc[o10]; a[u * 4 + 3] = xc[o11];
        }

        for (int cg = 0; cg < 16; cg++) {
            int cn = (cg < 15 ? cg + 1 : 15) * 4;
            float an[16];
#pragma unroll
            for (int u = 0; u < 4; u++) {
                const float* xc = xb + (cn + u) * HWSZ;
                an[u * 4 + 0] = xc[o00]; an[u * 4 + 1] = xc[o01];
                an[u * 4 + 2] = xc[o10]; an[u * 4 + 3] = xc[o11];
            }
#pragma unroll
            for (int u = 0; u < 4; u++) {
                float s = w00 * a[u * 4 + 0] + w01 * a[u * 4 + 1]
                        + w10 * a[u * 4 + 2] + w11 * a[u * 4 + 3];
                const float* wpc = wp + (cg * 4 + u) * O_;
#pragma unroll
                for (int o = 0; o < 32; o++) acc[o] += s * wpc[o];
            }
#pragma unroll
            for (int i2 = 0; i2 < 16; i2++) a[i2] = an[i2];
        }

        py = pyn; px = pxn; m = mn;
    }

    int obase = (b * O_ + o0) * HWSZ + p;
#pragma unroll
    for (int o = 0; o < 32; o++)
        out[obase + o * HWSZ] = acc[o] + bias[o0 + o];
}

// ---------------------------------------------------------------------------
extern "C" void kernel_launch(void* const* d_in, const int* in_sizes, int n_in,
                              void* d_out, int out_size, void* d_ws, size_t ws_size,
                              hipStream_t stream) {
    const float* x     = (const float*)d_in[0];
    const float* w_off = (const float*)d_in[1];
    const float* b_off = (const float*)d_in[2];
    const float* w_mod = (const float*)d_in[3];
    const float* b_mod = (const float*)d_in[4];
    const float* w     = (const float*)d_in[5];
    const float* bias  = (const float*)d_in[6];
    float* out = (float*)d_out;

    const int nCoord = B_ * K2_ * HWSZ;   // 1,179,648
    float* pyA = (float*)d_ws;
    float* pxA = pyA + nCoord;
    float* mA  = pxA + nCoord;
    float* wt  = mA + nCoord;             // 36,864 floats
    float* wom = wt + K2_ * C_ * O_;      // 15,552 floats

    const int nPrep = K2_ * C_ * O_ + C_ * 243;
    hipLaunchKernelGGL(prep_weights_k, dim3((nPrep + 255) / 256), dim3(256),
                       0, stream, w, w_off, w_mod, wt, wom);
    hipLaunchKernelGGL(conv_offmask_k, dim3(1024), dim3(512), 0, stream,
                       x, wom, b_off, b_mod, pyA, pxA, mA);
    hipLaunchKernelGGL(sample_gemm_k, dim3(512), dim3(512), 0, stream,
                       x, pyA, pxA, mA, wt, bias, out);
}